// Round 8
// baseline (560.339 us; speedup 1.0000x reference)
//
#include <hip/hip_runtime.h>
#include <hip/hip_fp16.h>

// Problem constants
#define BSZ 32
#define CS_ 640
#define CT_ 768
#define NTOK 576
#define HID 64
#define ITERS 50
#define WGB 16           // workgroups per batch
#define ROWS 36          // rows of M per workgroup (576/16)
#define NWG (BSZ*WGB)    // 512 wgs = exactly 2 per CU (uniform), 32 waves/CU
#define MPITCH 640       // halves per Ms/E row (576 real + 64 pad)
#define XPITCH 68        // halves per staged x row

#define LOG2_N 9.169925001442312f         // log2(576)
#define INV_N 0.001736111111111111f       // 1/576
#define MS_SCALE 14.426950408889634f      // 10 * log2(e):  Ms' = M/reg * log2(e)
#define M_FROM_MSP 0.06931471805599453f   // ln2 / 10

// Workspace layout (bytes)
#define OFF_CNT 0              // 32 flag groups, 64B apart (2048 B): flags[b][part]
#define OFF_DONE 2048          // int
#define OFF_GSUM 2056          // float
#define OFF_DUMMY 2112         // 512 f32 (unused sink, kept for layout stability)
#define OFF_SQS 4160           // sumsq [2][32][64] f32 (16384 B)
#define OFF_PACC 20544         // (unused legacy region)
#define MEMSET_BYTES 168000
#define OFF_XS 168000          // xs fp16 [32][576][64] = 2,359,296
#define OFF_XT 2527296         // xt fp16 [32][576][64] = 2,359,296 (end 4,886,592)
#define OFF_PSLOT 4886592      // col-sum slots [2][32][16][576] f32 = 2,359,296 (end 7,245,888)

// k4 LDS layout (bytes); total 62,576 -> 2 wgs/CU (125,152 <= 163,840)
#define L_MS 0                 // 36*640*2 = 46080  (Ms during build, E during iters)
#define L_U 46080              // 36*4 = 144  (log2-domain u', for final)
#define L_V 46224              // 640*4 = 2560 (fp32; used only for final v_log)
#define L_RED 48784            // 16*4 = 64
#define L_EUH 48848            // 40 halves (eu as fp16 per row, pairs 4B-aligned) pad 96
#define L_MROW 48944           // 36*4 = 144 (per-row max of Ms, for final M recovery)
#define L_EWH 49088            // 640 halves = 1280 (ew_v = 2^v as fp16; pad cols 0)
#define L_UNION 50368          // iters: vtmp 3*576*4 = 6912
                               // build: ssc(256)+stc(256)+sqs(144)+sqt(2304)+xs_l(4896)+xt_l(4352)
#define SMEM_BYTES 62576

typedef _Float16 half8 __attribute__((ext_vector_type(8)));
typedef _Float16 h2f __attribute__((ext_vector_type(2)));
typedef float f32x4 __attribute__((ext_vector_type(4)));

#if defined(__has_builtin)
#if __has_builtin(__builtin_amdgcn_fdot2)
#define HAVE_FDOT2 1
#endif
#endif

__device__ __forceinline__ float fdot2f(h2f a, h2f b, float c) {
#ifdef HAVE_FDOT2
    return __builtin_amdgcn_fdot2(a, b, c, false);
#else
    return fmaf((float)a[0], (float)b[0], fmaf((float)a[1], (float)b[1], c));
#endif
}

// ---------------------------------------------------------------------------
// K1 (unchanged, proven): MFMA-f16 projection GEMM.
// ---------------------------------------------------------------------------
#define APITCH 40   // halves per staged row (32 + 8 pad): 80B row -> 16B aligned

template <int C>
__device__ __forceinline__ void proj_mfma(
    const float* __restrict__ feat,   // [C][576] this batch
    const float* __restrict__ W,      // [64][C]
    const float* __restrict__ bias,   // [64]
    __half* __restrict__ out,         // [576][64] this batch
    float* __restrict__ sq,           // [64] this (side,batch)
    _Float16* lA, _Float16* lB, int nblk)
{
    const int tid = threadIdx.x;      // 256
    const int lane = tid & 63;
    const int wv = tid >> 6;          // 0..3
    const int n0 = nblk * 64;
    const int fr = lane & 15;         // fragment row/col index
    const int kg = lane >> 4;         // 0..3 -> k0 = kg*8

    f32x4 acc[4];
#pragma unroll
    for (int n = 0; n < 4; n++) acc[n] = (f32x4){0.f, 0.f, 0.f, 0.f};

    for (int c0 = 0; c0 < C; c0 += 32) {
        __syncthreads();   // protect LDS reuse from previous step's reads
#pragma unroll
        for (int q = 0; q < 8; q++) {
            int idx = tid + q * 256;          // 0..2047
            int t = idx & 63, c = idx >> 6;   // 64 t x 32 c
            lA[t * APITCH + c] = (_Float16)feat[(size_t)(c0 + c) * NTOK + n0 + t];
        }
#pragma unroll
        for (int q = 0; q < 8; q++) {
            int idx = tid + q * 256;
            int c = idx & 31, h = idx >> 5;   // 64 h x 32 c
            lB[h * APITCH + c] = (_Float16)W[(size_t)h * C + c0 + c];
        }
        __syncthreads();
        half8 a = *(const half8*)&lA[(wv * 16 + fr) * APITCH + kg * 8];
#pragma unroll
        for (int n = 0; n < 4; n++) {
            half8 b = *(const half8*)&lB[(n * 16 + fr) * APITCH + kg * 8];
            acc[n] = __builtin_amdgcn_mfma_f32_16x16x32_f16(a, b, acc[n], 0, 0, 0);
        }
    }

    // Epilogue: D: col=lane&15 -> h, row=(lane>>4)*4+reg -> tok offset.
#pragma unroll
    for (int n = 0; n < 4; n++) {
        const int h = n * 16 + fr;
        const float bv = bias[h];
        float s = 0.f;
#pragma unroll
        for (int reg = 0; reg < 4; reg++) {
            const int tok = wv * 16 + kg * 4 + reg;
            float val = acc[n][reg] + bv;
            out[(size_t)(n0 + tok) * HID + h] = __float2half(val);
            s = fmaf(val, val, s);
        }
        s += __shfl_xor(s, 16, 64);
        s += __shfl_xor(s, 32, 64);
        if (lane < 16) atomicAdd(sq + h, s);
    }
}

__global__ __launch_bounds__(256, 4) void k1_proj(
    const float* __restrict__ feat_s, const float* __restrict__ feat_t,
    const float* __restrict__ Ws, const float* __restrict__ bs,
    const float* __restrict__ Wt, const float* __restrict__ bt,
    __half* __restrict__ xs, __half* __restrict__ xt, float* __restrict__ sumsq)
{
    __shared__ __align__(16) _Float16 lA[64 * APITCH];
    __shared__ __align__(16) _Float16 lB[64 * APITCH];
    const int nblk = blockIdx.x, b = blockIdx.y, st = blockIdx.z;
    if (st == 0) {
        proj_mfma<CS_>(feat_s + (size_t)b * CS_ * NTOK, Ws, bs,
                       xs + (size_t)b * NTOK * HID, sumsq + b * 64, lA, lB, nblk);
    } else {
        proj_mfma<CT_>(feat_t + (size_t)b * CT_ * NTOK, Wt, bt,
                       xt + (size_t)b * NTOK * HID, sumsq + (BSZ + b) * 64, lA, lB, nblk);
    }
}

// ---------------------------------------------------------------------------
// K4: persistent Sinkhorn — round-7 structure (fdot2 passes, flags protocol),
// ONE change: the 16-way atomicAdd fan-in into Pacc (+ re-poison pass) is
// replaced by per-(batch,part) double-buffered SLOT STORES + reader-side
// summation. Publish = 576 plain agent-scope stores (no RMW, no per-address
// serialization); consume = 16 coalesced agent loads + 15 adds per thread.
// Slot lifetime: buffer q=it&1 written at it is read at it+1; overwrite at
// it+2 happens only after the end-of-(it+1) flag wait proves all parts
// finished reading it. Write->flag ordering via the __syncthreads vmcnt drain
// (same guarantee as before).
// ---------------------------------------------------------------------------
__global__ __launch_bounds__(1024, 8) void k4_sinkhorn(
    const __half* __restrict__ xsh, const __half* __restrict__ xth,
    const float* __restrict__ sumsq, float* __restrict__ Pslot,
    int* __restrict__ counters, int* __restrict__ done,
    float* __restrict__ gsum, float* __restrict__ dummyout,
    float* __restrict__ out)
{
    extern __shared__ char smem[];
    __half* Ms  = (__half*)(smem + L_MS);          // Ms during build, E during iters
    _Float16* MsH = (_Float16*)(smem + L_MS);
    float* u_l  = (float*)(smem + L_U);
    float* vlg  = (float*)(smem + L_V);            // final-only v_log buffer
    float* red  = (float*)(smem + L_RED);
    _Float16* eu_h = (_Float16*)(smem + L_EUH);    // eu = 2^u' as fp16 per row
    float* mrow = (float*)(smem + L_MROW);
    _Float16* ewh = (_Float16*)(smem + L_EWH);     // ew_v = 2^v as fp16 per col
    float* vtmp = (float*)(smem + L_UNION);        // [3][576] col partials
    float* ssc  = (float*)(smem + L_UNION);
    float* stc  = (float*)(smem + L_UNION + 256);
    float* sqs  = (float*)(smem + L_UNION + 512);
    float* sqt  = (float*)(smem + L_UNION + 656);
    __half* xs_l = (__half*)(smem + L_UNION + 2960);
    __half* xt_l = (__half*)(smem + L_UNION + 7856);

    const int tid = threadIdx.x;
    const int b = blockIdx.x & 31, part = blockIdx.x >> 5;
    const int r0 = part * ROWS;
    const int lane = tid & 63, wv = tid >> 6;

    if (tid < 64) {
        ssc[tid] = 1.0f / fmaxf(sqrtf(sumsq[b * 64 + tid]), 1e-12f);
    } else if (tid < 128) {
        stc[tid - 64] = 1.0f / fmaxf(sqrtf(sumsq[BSZ * 64 + b * 64 + (tid - 64)]), 1e-12f);
    }
    // ewh = 2^v; v starts at 0 -> 1.0 (pad columns: 0 so they contribute nothing)
    for (int m = tid; m < MPITCH; m += 1024) ewh[m] = (m < NTOK) ? (_Float16)1.0f : (_Float16)0.0f;
    __syncthreads();

    for (int idx = tid; idx < ROWS * 64; idx += 1024) {
        int r = idx >> 6, h = idx & 63;
        xs_l[r * XPITCH + h] =
            __float2half(__half2float(xsh[((size_t)b * NTOK + r0 + r) * 64 + h]) * ssc[h]);
    }
    if (tid < NTOK) {
        const __half* tp = xth + ((size_t)b * NTOK + tid) * 64;
        float s = 0.f;
#pragma unroll
        for (int h = 0; h < 64; h++) { float v = __half2float(tp[h]) * stc[h]; s = fmaf(v, v, s); }
        sqt[tid] = s;
    }
    __syncthreads();
    if (tid < ROWS) {
        float s = 0.f;
#pragma unroll
        for (int h = 0; h < 64; h++) { float v = __half2float(xs_l[tid * XPITCH + h]); s = fmaf(v, v, s); }
        sqs[tid] = s;
    }

    for (int c0 = 0; c0 < NTOK; c0 += 32) {
        __syncthreads();
        for (int idx = tid; idx < 32 * 64; idx += 1024) {
            int m = idx >> 6, h = idx & 63;
            xt_l[m * XPITCH + h] =
                __float2half(__half2float(xth[((size_t)b * NTOK + c0 + m) * 64 + h]) * stc[h]);
        }
        __syncthreads();
        for (int idx = tid; idx < ROWS * 32; idx += 1024) {
            int r = idx >> 5, c = idx & 31;
            const __half2* xr = (const __half2*)(xs_l + r * XPITCH);
            const __half2* tr = (const __half2*)(xt_l + c * XPITCH);
            float d = 0.f;
#pragma unroll
            for (int h2 = 0; h2 < 32; h2++) {
                float2 av = __half22float2(xr[h2]);
                float2 tv = __half22float2(tr[h2]);
                d = fmaf(av.x, tv.x, d);
                d = fmaf(av.y, tv.y, d);
            }
            float M = fmaxf(sqs[r] + sqt[c] - 2.f * d, 0.f);
            Ms[r * MPITCH + c0 + c] = __float2half(M * MS_SCALE);
        }
    }
    __syncthreads();
    for (int idx = tid; idx < ROWS * (MPITCH - NTOK); idx += 1024) {
        int r = idx >> 6, k = idx & 63;
        Ms[r * MPITCH + NTOK + k] = __float2half(-1000.f);
    }
    __syncthreads();

    // ---- One-time transform: Ms -> E = 2^(Ms - rowmax), record rowmax.
    for (int r = wv; r < ROWS; r += 16) {
        __half* row = Ms + r * MPITCH;
        float2 f[5];
        float mx = 0.f;   // real Ms >= 0, pad = -1000 never wins
#pragma unroll
        for (int j = 0; j < 5; j++) {
            f[j] = __half22float2(*(const __half2*)&row[128 * j + 2 * lane]);
            mx = fmaxf(mx, fmaxf(f[j].x, f[j].y));
        }
#pragma unroll
        for (int off = 32; off > 0; off >>= 1) mx = fmaxf(mx, __shfl_xor(mx, off, 64));
        if (lane == 0) mrow[r] = mx;
#pragma unroll
        for (int j = 0; j < 5; j++) {
            *(__half2*)&row[128 * j + 2 * lane] = __floats2half2_rn(
                __builtin_amdgcn_exp2f(f[j].x - mx), __builtin_amdgcn_exp2f(f[j].y - mx));
        }
    }
    __syncthreads();

    int* flags = counters + b * 16;   // 16 write-once flags, one 64B line per batch
    // slot base for this batch: Pslot[q][b][p][c], c fastest
    float* slotW = Pslot + ((size_t)b * WGB + part) * NTOK;          // + q*BSZ*WGB*NTOK
    const float* slotR = Pslot + (size_t)b * WGB * NTOK;             // + q*BSZ*WGB*NTOK + p*NTOK
    const size_t QSTRIDE = (size_t)BSZ * WGB * NTOK;

    for (int it = 1; it <= ITERS; ++it) {
        if (it > 1) {
            if (tid < NTOK) {
                const size_t qoff = (size_t)((it - 1) & 1) * QSTRIDE;
                const float* rp = slotR + qoff + tid;
                float s = 0.f;
#pragma unroll
                for (int p = 0; p < WGB; p++)
                    s += __hip_atomic_load(rp + (size_t)p * NTOK,
                                           __ATOMIC_RELAXED, __HIP_MEMORY_SCOPE_AGENT);
                ewh[tid] = (_Float16)(INV_N * __builtin_amdgcn_rcpf(s));   // 2^v
            }
            __syncthreads();
        }
        // ---- Row pass: rowsum_r = sum_c E_rc * ewv_c  (fdot2, fp32 accum)
        h2f vrh[5];
#pragma unroll
        for (int j = 0; j < 5; j++) vrh[j] = *(const h2f*)&ewh[128 * j + 2 * lane];
        for (int r = wv; r < ROWS; r += 16) {
            const _Float16* row = MsH + r * MPITCH;
            float a = 0.f;
#pragma unroll
            for (int j = 0; j < 5; j++)
                a = fdot2f(*(const h2f*)&row[128 * j + 2 * lane], vrh[j], a);
#pragma unroll
            for (int off = 32; off > 0; off >>= 1) a += __shfl_xor(a, off, 64);
            if (lane == 0) {
                eu_h[r] = (_Float16)(INV_N * __builtin_amdgcn_rcpf(a));  // 2^u'
                u_l[r] = -LOG2_N - __builtin_amdgcn_logf(a);   // log2-domain for final
            }
        }
        __syncthreads();
        // ---- Col pass: partial colsum over 12 rows per worker (864 workers),
        // row-paired fdot2 with v_perm repack.
        if (tid < 864) {
            int q = tid / 288, p = tid - q * 288;     // q: row-third, p: col pair
            const _Float16* col = MsH + 2 * p;
            float a0 = 0.f, a1 = 0.f;
            int n1 = q * 12;
#pragma unroll
            for (int nn = 0; nn < 6; nn++, n1 += 2) {
                uint ea = *(const uint*)&col[n1 * MPITCH];         // (E[n1,2p],E[n1,2p+1])
                uint eb = *(const uint*)&col[(n1 + 1) * MPITCH];   // (E[n1+1,2p],E[n1+1,2p+1])
                h2f up = *(const h2f*)&eu_h[n1];                   // (eu[n1],eu[n1+1])
                uint xpk = __builtin_amdgcn_perm(eb, ea, 0x05040100u);  // (Ax,Bx)
                uint ypk = __builtin_amdgcn_perm(eb, ea, 0x07060302u);  // (Ay,By)
                a0 = fdot2f(__builtin_bit_cast(h2f, xpk), up, a0);
                a1 = fdot2f(__builtin_bit_cast(h2f, ypk), up, a1);
            }
            ((float2*)(vtmp + q * NTOK))[p] = make_float2(a0, a1);
        }
        __syncthreads();
        if (tid < NTOK) {
            float s = vtmp[tid] + vtmp[NTOK + tid] + vtmp[2 * NTOK + tid];
            __hip_atomic_store(slotW + (size_t)(it & 1) * QSTRIDE + tid, s,
                               __ATOMIC_RELAXED, __HIP_MEMORY_SCOPE_AGENT);
        }
        __syncthreads();   // drains publishes (vmcnt(0) before s_barrier)
        if (tid < WGB) {
            if (tid == part)
                __hip_atomic_store(&flags[tid], it, __ATOMIC_RELAXED, __HIP_MEMORY_SCOPE_AGENT);
            while (__hip_atomic_load(&flags[tid], __ATOMIC_RELAXED, __HIP_MEMORY_SCOPE_AGENT) < it)
                __builtin_amdgcn_s_sleep(1);
        }
        __syncthreads();
    }

    // ---- Final: v (log2 domain) from slots (q = ITERS&1 = 0);
    // T*M with M = (log2(E) + rowmax) * ln2/10
    if (tid < NTOK) {
        const float* rp = slotR + tid;   // q=0
        float s = 0.f;
#pragma unroll
        for (int p = 0; p < WGB; p++)
            s += __hip_atomic_load(rp + (size_t)p * NTOK,
                                   __ATOMIC_RELAXED, __HIP_MEMORY_SCOPE_AGENT);
        vlg[tid] = -LOG2_N - __builtin_amdgcn_logf(s);
    }
    __syncthreads();
    float acc = 0.f;
    for (int idx = tid; idx < ROWS * NTOK; idx += 1024) {
        int r = idx / NTOK, m = idx - r * NTOK;
        float e = __half2float(Ms[r * MPITCH + m]);
        if (e > 0.f) {
            float msp = __builtin_amdgcn_logf(e) + mrow[r];
            acc = fmaf(__builtin_amdgcn_exp2f(u_l[r] + vlg[m]) * e, msp, acc);
        }
    }
#pragma unroll
    for (int off = 32; off > 0; off >>= 1) acc += __shfl_xor(acc, off, 64);
    if (lane == 0) red[wv] = acc;
    __syncthreads();
    if (tid == 0) {
        float s = 0.f;
#pragma unroll
        for (int w2 = 0; w2 < 16; w2++) s += red[w2];
        float old = __hip_atomic_fetch_add(gsum, s * M_FROM_MSP,
                                           __ATOMIC_RELAXED, __HIP_MEMORY_SCOPE_AGENT);
        int* dptr = done + ((old == -1.2345678e33f) ? 1 : 0);
        int prev = __hip_atomic_fetch_add(dptr, 1, __ATOMIC_RELAXED, __HIP_MEMORY_SCOPE_AGENT);
        if (prev == NWG - 1) {
            float tot = __hip_atomic_load(gsum, __ATOMIC_RELAXED, __HIP_MEMORY_SCOPE_AGENT);
            out[0] = tot * (1.0f / BSZ);
        }
        if (old == -1.2345678e33f) dummyout[blockIdx.x] = 1.f;  // keep param live
    }
}

extern "C" void kernel_launch(void* const* d_in, const int* in_sizes, int n_in,
                              void* d_out, int out_size, void* d_ws, size_t ws_size,
                              hipStream_t stream) {
    const float* feat_s = (const float*)d_in[0];
    const float* feat_t = (const float*)d_in[1];
    const float* Ws = (const float*)d_in[2];
    const float* bs = (const float*)d_in[3];
    const float* Wt = (const float*)d_in[4];
    const float* bt = (const float*)d_in[5];

    char* ws = (char*)d_ws;
    int* counters  = (int*)(ws + OFF_CNT);
    int* done      = (int*)(ws + OFF_DONE);
    float* gsum    = (float*)(ws + OFF_GSUM);
    float* dummyo  = (float*)(ws + OFF_DUMMY);
    float* sumsq   = (float*)(ws + OFF_SQS);
    float* Pslot   = (float*)(ws + OFF_PSLOT);
    __half* xs     = (__half*)(ws + OFF_XS);
    __half* xt     = (__half*)(ws + OFF_XT);
    float* out = (float*)d_out;

    hipMemsetAsync(ws, 0, MEMSET_BYTES, stream);

    hipLaunchKernelGGL(k1_proj, dim3(9, 32, 2), dim3(256), 0, stream,
                       feat_s, feat_t, Ws, bs, Wt, bt, xs, xt, sumsq);

    (void)hipFuncSetAttribute((const void*)k4_sinkhorn,
                              hipFuncAttributeMaxDynamicSharedMemorySize, SMEM_BYTES);
    hipLaunchKernelGGL(k4_sinkhorn, dim3(NWG), dim3(1024), SMEM_BYTES, stream,
                       xs, xt, sumsq, Pslot, counters, done, gsum, dummyo, out);
}

// Round 10
// 443.390 us; speedup vs baseline: 1.2638x; 1.2638x over previous
//
#include <hip/hip_runtime.h>
#include <hip/hip_fp16.h>

// Problem constants
#define BSZ 32
#define CS_ 640
#define CT_ 768
#define NTOK 576
#define HID 64
#define ITERS 50
#define WGB 16           // workgroups per batch
#define ROWS 36          // rows of M per workgroup (576/16)
#define NWG (BSZ*WGB)    // 512 wgs = exactly 2 per CU (uniform), 32 waves/CU
#define MPITCH 640       // halves per Ms/E row (576 real + 64 pad)
#define XPITCH 68        // halves per staged x row

#define LOG2_N 9.169925001442312f         // log2(576)
#define INV_N 0.001736111111111111f       // 1/576
#define MS_SCALE 14.426950408889634f      // 10 * log2(e):  Ms' = M/reg * log2(e)
#define M_FROM_MSP 0.06931471805599453f   // ln2 / 10

// Workspace layout (bytes) — NO memset dispatch: k1 zeroes what k4 needs.
#define OFF_CNT 0              // 32 flag groups, 64B apart (2048 B): flags[b][part]
#define OFF_DONE 2048          // 2 ints
#define OFF_GSUM 2056          // float
#define OFF_DUMMY 2112         // 512 f32 (keep-alive sink, never written in practice)
#define OFF_SQP 4160           // sqpart [2][32][9][64] f32 = 147,456 (plain stores, no init) -> 151,616
#define OFF_PACC 151616        // col-sum accumulators [2][32][576] f32 = 147,456 -> 299,072
#define OFF_XS 299072          // xs fp16 [32][576][64] = 2,359,296 -> 2,658,368
#define OFF_XT 2658368         // xt fp16 [32][576][64] = 2,359,296 -> 5,017,664

// k4 LDS layout (bytes); total 62,576 -> 2 wgs/CU (125,152 <= 163,840)
#define L_MS 0                 // 36*640*2 = 46080  (Ms during build, E during iters)
#define L_U 46080              // 36*4 = 144  (log2-domain u', for final)
#define L_V 46224              // 640*4 = 2560 (fp32; used only for final v_log)
#define L_RED 48784            // 16*4 = 64
#define L_EUH 48848            // 40 halves (eu as fp16 per row, pairs 4B-aligned) pad 96
#define L_MROW 48944           // 36*4 = 144 (per-row max of Ms, for final M recovery)
#define L_EWH 49088            // 640 halves = 1280 (ew_v = 2^v as fp16; pad cols 0)
#define L_UNION 50368          // iters: vtmp 3*576*4 = 6912
                               // build: ssc(256)+stc(256)+sqs(144)+sqt(2304)+xs_l(4896)+xt_l(4352)
#define SMEM_BYTES 62576

typedef _Float16 half8 __attribute__((ext_vector_type(8)));
typedef _Float16 h2f __attribute__((ext_vector_type(2)));
typedef float f32x4 __attribute__((ext_vector_type(4)));

#if defined(__has_builtin)
#if __has_builtin(__builtin_amdgcn_fdot2)
#define HAVE_FDOT2 1
#endif
#endif

__device__ __forceinline__ float fdot2f(h2f a, h2f b, float c) {
#ifdef HAVE_FDOT2
    return __builtin_amdgcn_fdot2(a, b, c, false);
#else
    return fmaf((float)a[0], (float)b[0], fmaf((float)a[1], (float)b[1], c));
#endif
}

// ---------------------------------------------------------------------------
// K1: MFMA-f16 projection GEMM + workspace init (replaces memset dispatch;
// stream order k1->k4 makes the zeroing race-free). sumsq: each wave's
// 16-token partial is reduced ACROSS the 4 waves in LDS (fix of R9's write
// race — all 4 waves hold partials for all 64 h), then ONE plain store per h
// into the per-(side,b,nblk) sqpart slot; k4 sums the 9 nblk partials.
// ---------------------------------------------------------------------------
#define APITCH 40   // halves per staged row (32 + 8 pad): 80B row -> 16B aligned

template <int C>
__device__ __forceinline__ void proj_mfma(
    const float* __restrict__ feat,   // [C][576] this batch
    const float* __restrict__ W,      // [64][C]
    const float* __restrict__ bias,   // [64]
    __half* __restrict__ out,         // [576][64] this batch
    float* __restrict__ sqp,          // [64] partial slot for (side,b,nblk)
    _Float16* lA, _Float16* lB, int nblk)
{
    const int tid = threadIdx.x;      // 256
    const int lane = tid & 63;
    const int wv = tid >> 6;          // 0..3
    const int n0 = nblk * 64;
    const int fr = lane & 15;         // fragment row/col index
    const int kg = lane >> 4;         // 0..3 -> k0 = kg*8

    f32x4 acc[4];
#pragma unroll
    for (int n = 0; n < 4; n++) acc[n] = (f32x4){0.f, 0.f, 0.f, 0.f};

    for (int c0 = 0; c0 < C; c0 += 32) {
        __syncthreads();   // protect LDS reuse from previous step's reads
#pragma unroll
        for (int q = 0; q < 8; q++) {
            int idx = tid + q * 256;          // 0..2047
            int t = idx & 63, c = idx >> 6;   // 64 t x 32 c
            lA[t * APITCH + c] = (_Float16)feat[(size_t)(c0 + c) * NTOK + n0 + t];
        }
#pragma unroll
        for (int q = 0; q < 8; q++) {
            int idx = tid + q * 256;
            int c = idx & 31, h = idx >> 5;   // 64 h x 32 c
            lB[h * APITCH + c] = (_Float16)W[(size_t)h * C + c0 + c];
        }
        __syncthreads();
        half8 a = *(const half8*)&lA[(wv * 16 + fr) * APITCH + kg * 8];
#pragma unroll
        for (int n = 0; n < 4; n++) {
            half8 b = *(const half8*)&lB[(n * 16 + fr) * APITCH + kg * 8];
            acc[n] = __builtin_amdgcn_mfma_f32_16x16x32_f16(a, b, acc[n], 0, 0, 0);
        }
    }

    // Epilogue: D: col=lane&15 -> h, row=(lane>>4)*4+reg -> tok offset.
    __syncthreads();                 // all waves done reading lA/lB this step
    float* sred = (float*)lA;        // reuse staging LDS: [4][64] f32
#pragma unroll
    for (int n = 0; n < 4; n++) {
        const int h = n * 16 + fr;
        const float bv = bias[h];
        float s = 0.f;
#pragma unroll
        for (int reg = 0; reg < 4; reg++) {
            const int tok = wv * 16 + kg * 4 + reg;
            float val = acc[n][reg] + bv;
            out[(size_t)(n0 + tok) * HID + h] = __float2half(val);
            s = fmaf(val, val, s);
        }
        s += __shfl_xor(s, 16, 64);  // sum over kg -> wave's 16-token partial
        s += __shfl_xor(s, 32, 64);
        if (lane < 16) sred[wv * 64 + h] = s;
    }
    __syncthreads();
    if (tid < 64)
        sqp[tid] = sred[tid] + sred[64 + tid] + sred[128 + tid] + sred[192 + tid];
}

__global__ __launch_bounds__(256, 4) void k1_proj(
    const float* __restrict__ feat_s, const float* __restrict__ feat_t,
    const float* __restrict__ Ws, const float* __restrict__ bs,
    const float* __restrict__ Wt, const float* __restrict__ bt,
    __half* __restrict__ xs, __half* __restrict__ xt,
    float* __restrict__ sqpart, float* __restrict__ Pacc,
    int* __restrict__ counters, int* __restrict__ done, float* __restrict__ gsum)
{
    __shared__ __align__(16) _Float16 lA[64 * APITCH];
    __shared__ __align__(16) _Float16 lB[64 * APITCH];
    const int nblk = blockIdx.x, b = blockIdx.y, st = blockIdx.z;
    const int tid = threadIdx.x;

    // ---- workspace init (replaces memset; k1 completes before k4 launches)
    if (st == 0 && nblk < 8) {
        // zero Pacc[0..1][b][nblk*72 .. nblk*72+72)
        float* pz = Pacc + (size_t)b * NTOK + nblk * 72;
        if (tid < 72) { pz[tid] = 0.f; pz[(size_t)BSZ * NTOK + tid] = 0.f; }
    }
    if (st == 1 && nblk == 0) {
        if (tid < 16) counters[b * 16 + tid] = 0;
        if (b == 0) {
            if (tid == 16) done[0] = 0;
            if (tid == 17) done[1] = 0;
            if (tid == 18) gsum[0] = 0.f;
        }
    }

    if (st == 0) {
        proj_mfma<CS_>(feat_s + (size_t)b * CS_ * NTOK, Ws, bs,
                       xs + (size_t)b * NTOK * HID,
                       sqpart + ((size_t)b * 9 + nblk) * 64, lA, lB, nblk);
    } else {
        proj_mfma<CT_>(feat_t + (size_t)b * CT_ * NTOK, Wt, bt,
                       xt + (size_t)b * NTOK * HID,
                       sqpart + ((size_t)(BSZ + b) * 9 + nblk) * 64, lA, lB, nblk);
    }
}

// ---------------------------------------------------------------------------
// K4: persistent Sinkhorn — EXACT round-7 structure (best measured: fdot2
// passes, flags protocol, atomicAdd fan-in + arithmetic re-poison), with
// no-return publish/re-poison atomics and sqpart-summed ssc/stc.
// ---------------------------------------------------------------------------
__global__ __launch_bounds__(1024, 8) void k4_sinkhorn(
    const __half* __restrict__ xsh, const __half* __restrict__ xth,
    const float* __restrict__ sqpart, float* __restrict__ Pacc,
    int* __restrict__ counters, int* __restrict__ done,
    float* __restrict__ gsum, float* __restrict__ dummyout,
    float* __restrict__ out)
{
    extern __shared__ char smem[];
    __half* Ms  = (__half*)(smem + L_MS);          // Ms during build, E during iters
    _Float16* MsH = (_Float16*)(smem + L_MS);
    float* u_l  = (float*)(smem + L_U);
    float* vlg  = (float*)(smem + L_V);            // final-only v_log buffer
    float* red  = (float*)(smem + L_RED);
    _Float16* eu_h = (_Float16*)(smem + L_EUH);    // eu = 2^u' as fp16 per row
    float* mrow = (float*)(smem + L_MROW);
    _Float16* ewh = (_Float16*)(smem + L_EWH);     // ew_v = 2^v as fp16 per col
    float* vtmp = (float*)(smem + L_UNION);        // [3][576] col partials
    float* ssc  = (float*)(smem + L_UNION);
    float* stc  = (float*)(smem + L_UNION + 256);
    float* sqs  = (float*)(smem + L_UNION + 512);
    float* sqt  = (float*)(smem + L_UNION + 656);
    __half* xs_l = (__half*)(smem + L_UNION + 2960);
    __half* xt_l = (__half*)(smem + L_UNION + 7856);

    const int tid = threadIdx.x;
    const int b = blockIdx.x & 31, part = blockIdx.x >> 5;
    const int r0 = part * ROWS;
    const int lane = tid & 63, wv = tid >> 6;
    float s_kept = 0.f;

    if (tid < 64) {
        const float* sp = sqpart + (size_t)b * 9 * 64 + tid;
        float s = 0.f;
#pragma unroll
        for (int k = 0; k < 9; k++) s += sp[k * 64];
        ssc[tid] = 1.0f / fmaxf(sqrtf(s), 1e-12f);
    } else if (tid < 128) {
        const float* sp = sqpart + (size_t)(BSZ + b) * 9 * 64 + (tid - 64);
        float s = 0.f;
#pragma unroll
        for (int k = 0; k < 9; k++) s += sp[k * 64];
        stc[tid - 64] = 1.0f / fmaxf(sqrtf(s), 1e-12f);
    }
    // ewh = 2^v; v starts at 0 -> 1.0 (pad columns: 0 so they contribute nothing)
    for (int m = tid; m < MPITCH; m += 1024) ewh[m] = (m < NTOK) ? (_Float16)1.0f : (_Float16)0.0f;
    __syncthreads();

    for (int idx = tid; idx < ROWS * 64; idx += 1024) {
        int r = idx >> 6, h = idx & 63;
        xs_l[r * XPITCH + h] =
            __float2half(__half2float(xsh[((size_t)b * NTOK + r0 + r) * 64 + h]) * ssc[h]);
    }
    if (tid < NTOK) {
        const __half* tp = xth + ((size_t)b * NTOK + tid) * 64;
        float s = 0.f;
#pragma unroll
        for (int h = 0; h < 64; h++) { float v = __half2float(tp[h]) * stc[h]; s = fmaf(v, v, s); }
        sqt[tid] = s;
    }
    __syncthreads();
    if (tid < ROWS) {
        float s = 0.f;
#pragma unroll
        for (int h = 0; h < 64; h++) { float v = __half2float(xs_l[tid * XPITCH + h]); s = fmaf(v, v, s); }
        sqs[tid] = s;
    }

    for (int c0 = 0; c0 < NTOK; c0 += 32) {
        __syncthreads();
        for (int idx = tid; idx < 32 * 64; idx += 1024) {
            int m = idx >> 6, h = idx & 63;
            xt_l[m * XPITCH + h] =
                __float2half(__half2float(xth[((size_t)b * NTOK + c0 + m) * 64 + h]) * stc[h]);
        }
        __syncthreads();
        for (int idx = tid; idx < ROWS * 32; idx += 1024) {
            int r = idx >> 5, c = idx & 31;
            const __half2* xr = (const __half2*)(xs_l + r * XPITCH);
            const __half2* tr = (const __half2*)(xt_l + c * XPITCH);
            float d = 0.f;
#pragma unroll
            for (int h2 = 0; h2 < 32; h2++) {
                float2 av = __half22float2(xr[h2]);
                float2 tv = __half22float2(tr[h2]);
                d = fmaf(av.x, tv.x, d);
                d = fmaf(av.y, tv.y, d);
            }
            float M = fmaxf(sqs[r] + sqt[c] - 2.f * d, 0.f);
            Ms[r * MPITCH + c0 + c] = __float2half(M * MS_SCALE);
        }
    }
    __syncthreads();
    for (int idx = tid; idx < ROWS * (MPITCH - NTOK); idx += 1024) {
        int r = idx >> 6, k = idx & 63;
        Ms[r * MPITCH + NTOK + k] = __float2half(-1000.f);
    }
    __syncthreads();

    // ---- One-time transform: Ms -> E = 2^(Ms - rowmax), record rowmax.
    for (int r = wv; r < ROWS; r += 16) {
        __half* row = Ms + r * MPITCH;
        float2 f[5];
        float mx = 0.f;   // real Ms >= 0, pad = -1000 never wins
#pragma unroll
        for (int j = 0; j < 5; j++) {
            f[j] = __half22float2(*(const __half2*)&row[128 * j + 2 * lane]);
            mx = fmaxf(mx, fmaxf(f[j].x, f[j].y));
        }
#pragma unroll
        for (int off = 32; off > 0; off >>= 1) mx = fmaxf(mx, __shfl_xor(mx, off, 64));
        if (lane == 0) mrow[r] = mx;
#pragma unroll
        for (int j = 0; j < 5; j++) {
            *(__half2*)&row[128 * j + 2 * lane] = __floats2half2_rn(
                __builtin_amdgcn_exp2f(f[j].x - mx), __builtin_amdgcn_exp2f(f[j].y - mx));
        }
    }
    __syncthreads();

    int* flags = counters + b * 16;   // 16 write-once flags, one 64B line per batch

    for (int it = 1; it <= ITERS; ++it) {
        if (it > 1) {
            if (tid < NTOK) {
                const int qr = (it - 1) & 1, qw = it & 1;
                float s = __hip_atomic_load(&Pacc[(size_t)(qr * BSZ + b) * NTOK + tid],
                                            __ATOMIC_RELAXED, __HIP_MEMORY_SCOPE_AGENT);
                ewh[tid] = (_Float16)(INV_N * __builtin_amdgcn_rcpf(s));   // 2^v
                if (tid >= r0 && tid < r0 + ROWS) {
                    if (s_kept != 0.f)
                        (void)__hip_atomic_fetch_add(
                            &Pacc[(size_t)(qw * BSZ + b) * NTOK + tid], -s_kept,
                            __ATOMIC_RELAXED, __HIP_MEMORY_SCOPE_AGENT);
                    s_kept = s;
                }
            }
            __syncthreads();
        }
        // ---- Row pass: rowsum_r = sum_c E_rc * ewv_c  (fdot2, fp32 accum)
        h2f vrh[5];
#pragma unroll
        for (int j = 0; j < 5; j++) vrh[j] = *(const h2f*)&ewh[128 * j + 2 * lane];
        for (int r = wv; r < ROWS; r += 16) {
            const _Float16* row = MsH + r * MPITCH;
            float a = 0.f;
#pragma unroll
            for (int j = 0; j < 5; j++)
                a = fdot2f(*(const h2f*)&row[128 * j + 2 * lane], vrh[j], a);
#pragma unroll
            for (int off = 32; off > 0; off >>= 1) a += __shfl_xor(a, off, 64);
            if (lane == 0) {
                eu_h[r] = (_Float16)(INV_N * __builtin_amdgcn_rcpf(a));  // 2^u'
                u_l[r] = -LOG2_N - __builtin_amdgcn_logf(a);   // log2-domain for final
            }
        }
        __syncthreads();
        // ---- Col pass: partial colsum over 12 rows per worker (864 workers),
        // row-paired fdot2 with v_perm repack.
        if (tid < 864) {
            int q = tid / 288, p = tid - q * 288;     // q: row-third, p: col pair
            const _Float16* col = MsH + 2 * p;
            float a0 = 0.f, a1 = 0.f;
            int n1 = q * 12;
#pragma unroll
            for (int nn = 0; nn < 6; nn++, n1 += 2) {
                uint ea = *(const uint*)&col[n1 * MPITCH];         // (E[n1,2p],E[n1,2p+1])
                uint eb = *(const uint*)&col[(n1 + 1) * MPITCH];   // (E[n1+1,2p],E[n1+1,2p+1])
                h2f up = *(const h2f*)&eu_h[n1];                   // (eu[n1],eu[n1+1])
                uint xpk = __builtin_amdgcn_perm(eb, ea, 0x05040100u);  // (Ax,Bx)
                uint ypk = __builtin_amdgcn_perm(eb, ea, 0x07060302u);  // (Ay,By)
                a0 = fdot2f(__builtin_bit_cast(h2f, xpk), up, a0);
                a1 = fdot2f(__builtin_bit_cast(h2f, ypk), up, a1);
            }
            ((float2*)(vtmp + q * NTOK))[p] = make_float2(a0, a1);
        }
        __syncthreads();
        if (tid < NTOK) {
            float s = vtmp[tid] + vtmp[NTOK + tid] + vtmp[2 * NTOK + tid];
            (void)__hip_atomic_fetch_add(&Pacc[(size_t)((it & 1) * BSZ + b) * NTOK + tid], s,
                                         __ATOMIC_RELAXED, __HIP_MEMORY_SCOPE_AGENT);
        }
        __syncthreads();   // drains publishes (vmcnt(0) before s_barrier)
        if (tid < WGB) {
            if (tid == part)
                __hip_atomic_store(&flags[tid], it, __ATOMIC_RELAXED, __HIP_MEMORY_SCOPE_AGENT);
            while (__hip_atomic_load(&flags[tid], __ATOMIC_RELAXED, __HIP_MEMORY_SCOPE_AGENT) < it)
                __builtin_amdgcn_s_sleep(1);
        }
        __syncthreads();
    }

    // ---- Final: v (log2 domain) from Pacc (q=0 holds it=50's sums);
    // T*M with M = (log2(E) + rowmax) * ln2/10
    if (tid < NTOK) {
        float s = __hip_atomic_load(&Pacc[(size_t)b * NTOK + tid],
                                    __ATOMIC_RELAXED, __HIP_MEMORY_SCOPE_AGENT);
        vlg[tid] = -LOG2_N - __builtin_amdgcn_logf(s);
    }
    __syncthreads();
    float acc = 0.f;
    for (int idx = tid; idx < ROWS * NTOK; idx += 1024) {
        int r = idx / NTOK, m = idx - r * NTOK;
        float e = __half2float(Ms[r * MPITCH + m]);
        if (e > 0.f) {
            float msp = __builtin_amdgcn_logf(e) + mrow[r];
            acc = fmaf(__builtin_amdgcn_exp2f(u_l[r] + vlg[m]) * e, msp, acc);
        }
    }
#pragma unroll
    for (int off = 32; off > 0; off >>= 1) acc += __shfl_xor(acc, off, 64);
    if (lane == 0) red[wv] = acc;
    __syncthreads();
    if (tid == 0) {
        float s = 0.f;
#pragma unroll
        for (int w2 = 0; w2 < 16; w2++) s += red[w2];
        float old = __hip_atomic_fetch_add(gsum, s * M_FROM_MSP,
                                           __ATOMIC_RELAXED, __HIP_MEMORY_SCOPE_AGENT);
        int* dptr = done + ((old == -1.2345678e33f) ? 1 : 0);
        int prev = __hip_atomic_fetch_add(dptr, 1, __ATOMIC_RELAXED, __HIP_MEMORY_SCOPE_AGENT);
        if (prev == NWG - 1) {
            float tot = __hip_atomic_load(gsum, __ATOMIC_RELAXED, __HIP_MEMORY_SCOPE_AGENT);
            out[0] = tot * (1.0f / BSZ);
        }
        if (old == -1.2345678e33f) dummyout[blockIdx.x] = 1.f;  // keep param live
    }
}

extern "C" void kernel_launch(void* const* d_in, const int* in_sizes, int n_in,
                              void* d_out, int out_size, void* d_ws, size_t ws_size,
                              hipStream_t stream) {
    const float* feat_s = (const float*)d_in[0];
    const float* feat_t = (const float*)d_in[1];
    const float* Ws = (const float*)d_in[2];
    const float* bs = (const float*)d_in[3];
    const float* Wt = (const float*)d_in[4];
    const float* bt = (const float*)d_in[5];

    char* ws = (char*)d_ws;
    int* counters  = (int*)(ws + OFF_CNT);
    int* done      = (int*)(ws + OFF_DONE);
    float* gsum    = (float*)(ws + OFF_GSUM);
    float* dummyo  = (float*)(ws + OFF_DUMMY);
    float* sqpart  = (float*)(ws + OFF_SQP);
    float* Pacc    = (float*)(ws + OFF_PACC);
    __half* xs     = (__half*)(ws + OFF_XS);
    __half* xt     = (__half*)(ws + OFF_XT);
    float* out = (float*)d_out;

    // no memset dispatch: k1 zeroes flags/done/gsum/Pacc (stream-ordered before k4)

    hipLaunchKernelGGL(k1_proj, dim3(9, 32, 2), dim3(256), 0, stream,
                       feat_s, feat_t, Ws, bs, Wt, bt, xs, xt,
                       sqpart, Pacc, counters, done, gsum);

    (void)hipFuncSetAttribute((const void*)k4_sinkhorn,
                              hipFuncAttributeMaxDynamicSharedMemorySize, SMEM_BYTES);
    hipLaunchKernelGGL(k4_sinkhorn, dim3(NWG), dim3(1024), SMEM_BYTES, stream,
                       xs, xt, sqpart, Pacc, counters, done, gsum, dummyo, out);
}

// Round 11
// 406.056 us; speedup vs baseline: 1.3800x; 1.0919x over previous
//
#include <hip/hip_runtime.h>
#include <hip/hip_fp16.h>

// Problem constants
#define BSZ 32
#define CS_ 640
#define CT_ 768
#define NTOK 576
#define HID 64
#define ITERS 50
#define WGB 8            // workgroups per batch (halved fan-in vs R10)
#define ROWS 72          // rows of M per workgroup (576/8)
#define NWG (BSZ*WGB)    // 256 wgs = exactly 1 per CU (16 waves, 114KB LDS)
#define MPITCH 640       // halves per Ms/E row (576 real + 64 pad)
#define XPITCH 68        // halves per staged x row

#define LOG2_N 9.169925001442312f         // log2(576)
#define INV_N 0.001736111111111111f       // 1/576
#define MS_SCALE 14.426950408889634f      // 10 * log2(e):  Ms' = M/reg * log2(e)
#define M_FROM_MSP 0.06931471805599453f   // ln2 / 10

// Workspace layout (bytes) — NO memset dispatch: k1 zeroes what k4 needs.
#define OFF_CNT 0              // 32 flag groups, 64B apart (2048 B): flags[b][part]
#define OFF_DONE 2048          // 2 ints
#define OFF_GSUM 2056          // float
#define OFF_DUMMY 2112         // 512 f32 (keep-alive sink, never written in practice)
#define OFF_SQP 4160           // sqpart [2][32][9][64] f32 = 147,456 (plain stores) -> 151,616
#define OFF_PACC 151616        // col-sum accumulators [2][32][576] f32 = 147,456 -> 299,072
#define OFF_XS 299072          // xs fp16 [32][576][64] = 2,359,296 -> 2,658,368
#define OFF_XT 2658368         // xt fp16 [32][576][64] = 2,359,296 -> 5,017,664

// k4 LDS layout (bytes); total 114,048 -> 1 wg/CU
#define L_MS 0                 // 72*640*2 = 92160  (Ms during build, E during iters)
#define L_U 92160              // 72*4 = 288  (log2-domain u', for final)
#define L_V 92448              // 640*4 = 2560 (fp32; used only for final v_log)
#define L_RED 95008            // 16*4 = 64
#define L_EUH 95072            // 72 halves = 144 (pad 160): eu as fp16 per row
#define L_MROW 95232           // 72*4 = 288 (per-row max of Ms, for final M recovery)
#define L_EWH 95520            // 640 halves = 1280 (ew_v = 2^v as fp16; pad cols 0)
#define L_UNION 96800          // iters: vtmp 3*576*4 = 6912
                               // build: ssc(256)+stc(256)+sqs(288)+sqt(2304)+xs_l(9792)+xt_l(4352)
#define SMEM_BYTES 114048

typedef _Float16 half8 __attribute__((ext_vector_type(8)));
typedef _Float16 h2f __attribute__((ext_vector_type(2)));
typedef float f32x4 __attribute__((ext_vector_type(4)));

#if defined(__has_builtin)
#if __has_builtin(__builtin_amdgcn_fdot2)
#define HAVE_FDOT2 1
#endif
#endif

__device__ __forceinline__ float fdot2f(h2f a, h2f b, float c) {
#ifdef HAVE_FDOT2
    return __builtin_amdgcn_fdot2(a, b, c, false);
#else
    return fmaf((float)a[0], (float)b[0], fmaf((float)a[1], (float)b[1], c));
#endif
}

// ---------------------------------------------------------------------------
// K1 (unchanged from R10): MFMA-f16 projection GEMM + workspace init.
// ---------------------------------------------------------------------------
#define APITCH 40   // halves per staged row (32 + 8 pad): 80B row -> 16B aligned

template <int C>
__device__ __forceinline__ void proj_mfma(
    const float* __restrict__ feat,   // [C][576] this batch
    const float* __restrict__ W,      // [64][C]
    const float* __restrict__ bias,   // [64]
    __half* __restrict__ out,         // [576][64] this batch
    float* __restrict__ sqp,          // [64] partial slot for (side,b,nblk)
    _Float16* lA, _Float16* lB, int nblk)
{
    const int tid = threadIdx.x;      // 256
    const int lane = tid & 63;
    const int wv = tid >> 6;          // 0..3
    const int n0 = nblk * 64;
    const int fr = lane & 15;         // fragment row/col index
    const int kg = lane >> 4;         // 0..3 -> k0 = kg*8

    f32x4 acc[4];
#pragma unroll
    for (int n = 0; n < 4; n++) acc[n] = (f32x4){0.f, 0.f, 0.f, 0.f};

    for (int c0 = 0; c0 < C; c0 += 32) {
        __syncthreads();   // protect LDS reuse from previous step's reads
#pragma unroll
        for (int q = 0; q < 8; q++) {
            int idx = tid + q * 256;          // 0..2047
            int t = idx & 63, c = idx >> 6;   // 64 t x 32 c
            lA[t * APITCH + c] = (_Float16)feat[(size_t)(c0 + c) * NTOK + n0 + t];
        }
#pragma unroll
        for (int q = 0; q < 8; q++) {
            int idx = tid + q * 256;
            int c = idx & 31, h = idx >> 5;   // 64 h x 32 c
            lB[h * APITCH + c] = (_Float16)W[(size_t)h * C + c0 + c];
        }
        __syncthreads();
        half8 a = *(const half8*)&lA[(wv * 16 + fr) * APITCH + kg * 8];
#pragma unroll
        for (int n = 0; n < 4; n++) {
            half8 b = *(const half8*)&lB[(n * 16 + fr) * APITCH + kg * 8];
            acc[n] = __builtin_amdgcn_mfma_f32_16x16x32_f16(a, b, acc[n], 0, 0, 0);
        }
    }

    // Epilogue: D: col=lane&15 -> h, row=(lane>>4)*4+reg -> tok offset.
    __syncthreads();                 // all waves done reading lA/lB this step
    float* sred = (float*)lA;        // reuse staging LDS: [4][64] f32
#pragma unroll
    for (int n = 0; n < 4; n++) {
        const int h = n * 16 + fr;
        const float bv = bias[h];
        float s = 0.f;
#pragma unroll
        for (int reg = 0; reg < 4; reg++) {
            const int tok = wv * 16 + kg * 4 + reg;
            float val = acc[n][reg] + bv;
            out[(size_t)(n0 + tok) * HID + h] = __float2half(val);
            s = fmaf(val, val, s);
        }
        s += __shfl_xor(s, 16, 64);  // sum over kg -> wave's 16-token partial
        s += __shfl_xor(s, 32, 64);
        if (lane < 16) sred[wv * 64 + h] = s;
    }
    __syncthreads();
    if (tid < 64)
        sqp[tid] = sred[tid] + sred[64 + tid] + sred[128 + tid] + sred[192 + tid];
}

__global__ __launch_bounds__(256, 4) void k1_proj(
    const float* __restrict__ feat_s, const float* __restrict__ feat_t,
    const float* __restrict__ Ws, const float* __restrict__ bs,
    const float* __restrict__ Wt, const float* __restrict__ bt,
    __half* __restrict__ xs, __half* __restrict__ xt,
    float* __restrict__ sqpart, float* __restrict__ Pacc,
    int* __restrict__ counters, int* __restrict__ done, float* __restrict__ gsum)
{
    __shared__ __align__(16) _Float16 lA[64 * APITCH];
    __shared__ __align__(16) _Float16 lB[64 * APITCH];
    const int nblk = blockIdx.x, b = blockIdx.y, st = blockIdx.z;
    const int tid = threadIdx.x;

    // ---- workspace init (replaces memset; k1 completes before k4 launches)
    if (st == 0 && nblk < 8) {
        // zero Pacc[0..1][b][nblk*72 .. nblk*72+72)
        float* pz = Pacc + (size_t)b * NTOK + nblk * 72;
        if (tid < 72) { pz[tid] = 0.f; pz[(size_t)BSZ * NTOK + tid] = 0.f; }
    }
    if (st == 1 && nblk == 0) {
        if (tid < 16) counters[b * 16 + tid] = 0;
        if (b == 0) {
            if (tid == 16) done[0] = 0;
            if (tid == 17) done[1] = 0;
            if (tid == 18) gsum[0] = 0.f;
        }
    }

    if (st == 0) {
        proj_mfma<CS_>(feat_s + (size_t)b * CS_ * NTOK, Ws, bs,
                       xs + (size_t)b * NTOK * HID,
                       sqpart + ((size_t)b * 9 + nblk) * 64, lA, lB, nblk);
    } else {
        proj_mfma<CT_>(feat_t + (size_t)b * CT_ * NTOK, Wt, bt,
                       xt + (size_t)b * NTOK * HID,
                       sqpart + ((size_t)(BSZ + b) * 9 + nblk) * 64, lA, lB, nblk);
    }
}

// ---------------------------------------------------------------------------
// K4: persistent Sinkhorn — R10 structure (fdot2 passes, flags protocol,
// no-return atomics), re-parameterized to WGB=8: each WG owns 72 rows
// (1 WG/CU, 16 waves, 114KB LDS). Per-CU compute identical to R10's 2x36;
// atomic fan-in per Pacc address halves (16->8), flags halve, barrier skew
// shrinks. Col pass: 3 slices x 24 rows (864 workers).
// ---------------------------------------------------------------------------
__global__ __launch_bounds__(1024, 8) void k4_sinkhorn(
    const __half* __restrict__ xsh, const __half* __restrict__ xth,
    const float* __restrict__ sqpart, float* __restrict__ Pacc,
    int* __restrict__ counters, int* __restrict__ done,
    float* __restrict__ gsum, float* __restrict__ dummyout,
    float* __restrict__ out)
{
    extern __shared__ char smem[];
    __half* Ms  = (__half*)(smem + L_MS);          // Ms during build, E during iters
    _Float16* MsH = (_Float16*)(smem + L_MS);
    float* u_l  = (float*)(smem + L_U);
    float* vlg  = (float*)(smem + L_V);            // final-only v_log buffer
    float* red  = (float*)(smem + L_RED);
    _Float16* eu_h = (_Float16*)(smem + L_EUH);    // eu = 2^u' as fp16 per row
    float* mrow = (float*)(smem + L_MROW);
    _Float16* ewh = (_Float16*)(smem + L_EWH);     // ew_v = 2^v as fp16 per col
    float* vtmp = (float*)(smem + L_UNION);        // [3][576] col partials
    float* ssc  = (float*)(smem + L_UNION);
    float* stc  = (float*)(smem + L_UNION + 256);
    float* sqs  = (float*)(smem + L_UNION + 512);  // 72 f32 = 288
    float* sqt  = (float*)(smem + L_UNION + 800);  // 576 f32 = 2304
    __half* xs_l = (__half*)(smem + L_UNION + 3104);   // 72*68*2 = 9792
    __half* xt_l = (__half*)(smem + L_UNION + 12896);  // 32*68*2 = 4352

    const int tid = threadIdx.x;
    const int b = blockIdx.x & 31, part = blockIdx.x >> 5;   // part 0..7
    const int r0 = part * ROWS;
    const int lane = tid & 63, wv = tid >> 6;
    float s_kept = 0.f;

    if (tid < 64) {
        const float* sp = sqpart + (size_t)b * 9 * 64 + tid;
        float s = 0.f;
#pragma unroll
        for (int k = 0; k < 9; k++) s += sp[k * 64];
        ssc[tid] = 1.0f / fmaxf(sqrtf(s), 1e-12f);
    } else if (tid < 128) {
        const float* sp = sqpart + (size_t)(BSZ + b) * 9 * 64 + (tid - 64);
        float s = 0.f;
#pragma unroll
        for (int k = 0; k < 9; k++) s += sp[k * 64];
        stc[tid - 64] = 1.0f / fmaxf(sqrtf(s), 1e-12f);
    }
    // ewh = 2^v; v starts at 0 -> 1.0 (pad columns: 0 so they contribute nothing)
    for (int m = tid; m < MPITCH; m += 1024) ewh[m] = (m < NTOK) ? (_Float16)1.0f : (_Float16)0.0f;
    __syncthreads();

    for (int idx = tid; idx < ROWS * 64; idx += 1024) {
        int r = idx >> 6, h = idx & 63;
        xs_l[r * XPITCH + h] =
            __float2half(__half2float(xsh[((size_t)b * NTOK + r0 + r) * 64 + h]) * ssc[h]);
    }
    if (tid < NTOK) {
        const __half* tp = xth + ((size_t)b * NTOK + tid) * 64;
        float s = 0.f;
#pragma unroll
        for (int h = 0; h < 64; h++) { float v = __half2float(tp[h]) * stc[h]; s = fmaf(v, v, s); }
        sqt[tid] = s;
    }
    __syncthreads();
    if (tid < ROWS) {
        float s = 0.f;
#pragma unroll
        for (int h = 0; h < 64; h++) { float v = __half2float(xs_l[tid * XPITCH + h]); s = fmaf(v, v, s); }
        sqs[tid] = s;
    }

    for (int c0 = 0; c0 < NTOK; c0 += 32) {
        __syncthreads();
        for (int idx = tid; idx < 32 * 64; idx += 1024) {
            int m = idx >> 6, h = idx & 63;
            xt_l[m * XPITCH + h] =
                __float2half(__half2float(xth[((size_t)b * NTOK + c0 + m) * 64 + h]) * stc[h]);
        }
        __syncthreads();
        for (int idx = tid; idx < ROWS * 32; idx += 1024) {
            int r = idx >> 5, c = idx & 31;
            const __half2* xr = (const __half2*)(xs_l + r * XPITCH);
            const __half2* tr = (const __half2*)(xt_l + c * XPITCH);
            float d = 0.f;
#pragma unroll
            for (int h2 = 0; h2 < 32; h2++) {
                float2 av = __half22float2(xr[h2]);
                float2 tv = __half22float2(tr[h2]);
                d = fmaf(av.x, tv.x, d);
                d = fmaf(av.y, tv.y, d);
            }
            float M = fmaxf(sqs[r] + sqt[c] - 2.f * d, 0.f);
            Ms[r * MPITCH + c0 + c] = __float2half(M * MS_SCALE);
        }
    }
    __syncthreads();
    for (int idx = tid; idx < ROWS * (MPITCH - NTOK); idx += 1024) {
        int r = idx >> 6, k = idx & 63;
        Ms[r * MPITCH + NTOK + k] = __float2half(-1000.f);
    }
    __syncthreads();

    // ---- One-time transform: Ms -> E = 2^(Ms - rowmax), record rowmax.
    for (int r = wv; r < ROWS; r += 16) {
        __half* row = Ms + r * MPITCH;
        float2 f[5];
        float mx = 0.f;   // real Ms >= 0, pad = -1000 never wins
#pragma unroll
        for (int j = 0; j < 5; j++) {
            f[j] = __half22float2(*(const __half2*)&row[128 * j + 2 * lane]);
            mx = fmaxf(mx, fmaxf(f[j].x, f[j].y));
        }
#pragma unroll
        for (int off = 32; off > 0; off >>= 1) mx = fmaxf(mx, __shfl_xor(mx, off, 64));
        if (lane == 0) mrow[r] = mx;
#pragma unroll
        for (int j = 0; j < 5; j++) {
            *(__half2*)&row[128 * j + 2 * lane] = __floats2half2_rn(
                __builtin_amdgcn_exp2f(f[j].x - mx), __builtin_amdgcn_exp2f(f[j].y - mx));
        }
    }
    __syncthreads();

    int* flags = counters + b * 16;   // 8 write-once flags, one 64B line per batch

    for (int it = 1; it <= ITERS; ++it) {
        if (it > 1) {
            if (tid < NTOK) {
                const int qr = (it - 1) & 1, qw = it & 1;
                float s = __hip_atomic_load(&Pacc[(size_t)(qr * BSZ + b) * NTOK + tid],
                                            __ATOMIC_RELAXED, __HIP_MEMORY_SCOPE_AGENT);
                ewh[tid] = (_Float16)(INV_N * __builtin_amdgcn_rcpf(s));   // 2^v
                if (tid >= r0 && tid < r0 + ROWS) {
                    if (s_kept != 0.f)
                        (void)__hip_atomic_fetch_add(
                            &Pacc[(size_t)(qw * BSZ + b) * NTOK + tid], -s_kept,
                            __ATOMIC_RELAXED, __HIP_MEMORY_SCOPE_AGENT);
                    s_kept = s;
                }
            }
            __syncthreads();
        }
        // ---- Row pass: rowsum_r = sum_c E_rc * ewv_c  (fdot2, fp32 accum)
        h2f vrh[5];
#pragma unroll
        for (int j = 0; j < 5; j++) vrh[j] = *(const h2f*)&ewh[128 * j + 2 * lane];
        for (int r = wv; r < ROWS; r += 16) {
            const _Float16* row = MsH + r * MPITCH;
            float a = 0.f;
#pragma unroll
            for (int j = 0; j < 5; j++)
                a = fdot2f(*(const h2f*)&row[128 * j + 2 * lane], vrh[j], a);
#pragma unroll
            for (int off = 32; off > 0; off >>= 1) a += __shfl_xor(a, off, 64);
            if (lane == 0) {
                eu_h[r] = (_Float16)(INV_N * __builtin_amdgcn_rcpf(a));  // 2^u'
                u_l[r] = -LOG2_N - __builtin_amdgcn_logf(a);   // log2-domain for final
            }
        }
        __syncthreads();
        // ---- Col pass: partial colsum over 24 rows per worker (864 workers),
        // row-paired fdot2 with v_perm repack.
        if (tid < 864) {
            int q = tid / 288, p = tid - q * 288;     // q: row-third, p: col pair
            const _Float16* col = MsH + 2 * p;
            float a0 = 0.f, a1 = 0.f;
            int n1 = q * 24;
#pragma unroll
            for (int nn = 0; nn < 12; nn++, n1 += 2) {
                uint ea = *(const uint*)&col[n1 * MPITCH];         // (E[n1,2p],E[n1,2p+1])
                uint eb = *(const uint*)&col[(n1 + 1) * MPITCH];   // (E[n1+1,2p],E[n1+1,2p+1])
                h2f up = *(const h2f*)&eu_h[n1];                   // (eu[n1],eu[n1+1])
                uint xpk = __builtin_amdgcn_perm(eb, ea, 0x05040100u);  // (Ax,Bx)
                uint ypk = __builtin_amdgcn_perm(eb, ea, 0x07060302u);  // (Ay,By)
                a0 = fdot2f(__builtin_bit_cast(h2f, xpk), up, a0);
                a1 = fdot2f(__builtin_bit_cast(h2f, ypk), up, a1);
            }
            ((float2*)(vtmp + q * NTOK))[p] = make_float2(a0, a1);
        }
        __syncthreads();
        if (tid < NTOK) {
            float s = vtmp[tid] + vtmp[NTOK + tid] + vtmp[2 * NTOK + tid];
            (void)__hip_atomic_fetch_add(&Pacc[(size_t)((it & 1) * BSZ + b) * NTOK + tid], s,
                                         __ATOMIC_RELAXED, __HIP_MEMORY_SCOPE_AGENT);
        }
        __syncthreads();   // drains publishes (vmcnt(0) before s_barrier)
        if (tid < WGB) {
            if (tid == part)
                __hip_atomic_store(&flags[tid], it, __ATOMIC_RELAXED, __HIP_MEMORY_SCOPE_AGENT);
            while (__hip_atomic_load(&flags[tid], __ATOMIC_RELAXED, __HIP_MEMORY_SCOPE_AGENT) < it)
                __builtin_amdgcn_s_sleep(1);
        }
        __syncthreads();
    }

    // ---- Final: v (log2 domain) from Pacc (q=0 holds it=50's sums);
    // T*M with M = (log2(E) + rowmax) * ln2/10
    if (tid < NTOK) {
        float s = __hip_atomic_load(&Pacc[(size_t)b * NTOK + tid],
                                    __ATOMIC_RELAXED, __HIP_MEMORY_SCOPE_AGENT);
        vlg[tid] = -LOG2_N - __builtin_amdgcn_logf(s);
    }
    __syncthreads();
    float acc = 0.f;
    for (int idx = tid; idx < ROWS * NTOK; idx += 1024) {
        int r = idx / NTOK, m = idx - r * NTOK;
        float e = __half2float(Ms[r * MPITCH + m]);
        if (e > 0.f) {
            float msp = __builtin_amdgcn_logf(e) + mrow[r];
            acc = fmaf(__builtin_amdgcn_exp2f(u_l[r] + vlg[m]) * e, msp, acc);
        }
    }
#pragma unroll
    for (int off = 32; off > 0; off >>= 1) acc += __shfl_xor(acc, off, 64);
    if (lane == 0) red[wv] = acc;
    __syncthreads();
    if (tid == 0) {
        float s = 0.f;
#pragma unroll
        for (int w2 = 0; w2 < 16; w2++) s += red[w2];
        float old = __hip_atomic_fetch_add(gsum, s * M_FROM_MSP,
                                           __ATOMIC_RELAXED, __HIP_MEMORY_SCOPE_AGENT);
        int* dptr = done + ((old == -1.2345678e33f) ? 1 : 0);
        int prev = __hip_atomic_fetch_add(dptr, 1, __ATOMIC_RELAXED, __HIP_MEMORY_SCOPE_AGENT);
        if (prev == NWG - 1) {
            float tot = __hip_atomic_load(gsum, __ATOMIC_RELAXED, __HIP_MEMORY_SCOPE_AGENT);
            out[0] = tot * (1.0f / BSZ);
        }
        if (old == -1.2345678e33f) dummyout[blockIdx.x] = 1.f;  // keep param live
    }
}

extern "C" void kernel_launch(void* const* d_in, const int* in_sizes, int n_in,
                              void* d_out, int out_size, void* d_ws, size_t ws_size,
                              hipStream_t stream) {
    const float* feat_s = (const float*)d_in[0];
    const float* feat_t = (const float*)d_in[1];
    const float* Ws = (const float*)d_in[2];
    const float* bs = (const float*)d_in[3];
    const float* Wt = (const float*)d_in[4];
    const float* bt = (const float*)d_in[5];

    char* ws = (char*)d_ws;
    int* counters  = (int*)(ws + OFF_CNT);
    int* done      = (int*)(ws + OFF_DONE);
    float* gsum    = (float*)(ws + OFF_GSUM);
    float* dummyo  = (float*)(ws + OFF_DUMMY);
    float* sqpart  = (float*)(ws + OFF_SQP);
    float* Pacc    = (float*)(ws + OFF_PACC);
    __half* xs     = (__half*)(ws + OFF_XS);
    __half* xt     = (__half*)(ws + OFF_XT);
    float* out = (float*)d_out;

    // no memset dispatch: k1 zeroes flags/done/gsum/Pacc (stream-ordered before k4)

    hipLaunchKernelGGL(k1_proj, dim3(9, 32, 2), dim3(256), 0, stream,
                       feat_s, feat_t, Ws, bs, Wt, bt, xs, xt,
                       sqpart, Pacc, counters, done, gsum);

    (void)hipFuncSetAttribute((const void*)k4_sinkhorn,
                              hipFuncAttributeMaxDynamicSharedMemorySize, SMEM_BYTES);
    hipLaunchKernelGGL(k4_sinkhorn, dim3(NWG), dim3(1024), SMEM_BYTES, stream,
                       xs, xt, sqpart, Pacc, counters, done, gsum, dummyo, out);
}

// Round 12
// 392.793 us; speedup vs baseline: 1.4265x; 1.0338x over previous
//
#include <hip/hip_runtime.h>
#include <hip/hip_fp16.h>

// Problem constants
#define BSZ 32
#define CS_ 640
#define CT_ 768
#define NTOK 576
#define HID 64
#define ITERS 50
#define WGB 8            // workgroups per batch
#define ROWS 72          // rows of M per workgroup (576/8)
#define NWG (BSZ*WGB)    // 256 wgs = exactly 1 per CU (16 waves)
#define MPITCH 640       // halves per Ms/E row (576 real + 64 pad)
#define XPITCH 68        // halves per staged x row
#define VTP 644          // vtmp pitch (f32): 644%32=4 -> 4-bank rotate/wave, reads 2-way max

#define LOG2_N 9.169925001442312f         // log2(576)
#define INV_N 0.001736111111111111f       // 1/576
#define MS_SCALE 14.426950408889634f      // 10 * log2(e):  Ms' = M/reg * log2(e)
#define M_FROM_MSP 0.06931471805599453f   // ln2 / 10

// Workspace layout (bytes) — NO memset dispatch: k1 zeroes what k4 needs.
#define OFF_CNT 0              // 32 flag groups, 64B apart (2048 B): flags[b][part]
#define OFF_DONE 2048          // 2 ints
#define OFF_GSUM 2056          // float
#define OFF_DUMMY 2112         // 512 f32 (keep-alive sink, never written in practice)
#define OFF_SQP 4160           // sqpart [2][32][9][64] f32 = 147,456 (plain stores) -> 151,616
#define OFF_PACC 151616        // col-sum accumulators [2][32][576] f32 = 147,456 -> 299,072
#define OFF_XS 299072          // xs fp16 [32][576][64] = 2,359,296 -> 2,658,368
#define OFF_XT 2658368         // xt fp16 [32][576][64] = 2,359,296 -> 5,017,664

// k4 LDS layout (bytes); total 137,856 -> 1 wg/CU
#define L_MS 0                 // 72*640*2 = 92160  (Ms during build, E during iters)
#define L_U 92160              // 72*4 = 288  (log2-domain u', for final)
#define L_V 92448              // 640*4 = 2560 (fp32; used only for final v_log)
#define L_RED 95008            // 16*4 = 64
#define L_MROW 95072           // 72*4 = 288 (per-row max of Ms, for final M recovery)
#define L_EWH 95360            // 640 halves = 1280 (ew_v = 2^v as fp16; pad cols 0) -> 96640
#define L_VT 96640             // vtmp [16][644] f32 = 41,216 -> 137,856 (build overlays this)
#define L_UNION L_VT           // build: ssc(256)+stc(256)+sqs(288)+sqt(2304)+xs_l(9792)+xt_l(4352)=17248
#define SMEM_BYTES 137856

typedef _Float16 half8 __attribute__((ext_vector_type(8)));
typedef _Float16 h2f __attribute__((ext_vector_type(2)));
typedef float f32x4 __attribute__((ext_vector_type(4)));

#if defined(__has_builtin)
#if __has_builtin(__builtin_amdgcn_fdot2)
#define HAVE_FDOT2 1
#endif
#endif

__device__ __forceinline__ float fdot2f(h2f a, h2f b, float c) {
#ifdef HAVE_FDOT2
    return __builtin_amdgcn_fdot2(a, b, c, false);
#else
    return fmaf((float)a[0], (float)b[0], fmaf((float)a[1], (float)b[1], c));
#endif
}

// ---------------------------------------------------------------------------
// K1 (unchanged, proven): MFMA-f16 projection GEMM + workspace init.
// ---------------------------------------------------------------------------
#define APITCH 40   // halves per staged row (32 + 8 pad): 80B row -> 16B aligned

template <int C>
__device__ __forceinline__ void proj_mfma(
    const float* __restrict__ feat,   // [C][576] this batch
    const float* __restrict__ W,      // [64][C]
    const float* __restrict__ bias,   // [64]
    __half* __restrict__ out,         // [576][64] this batch
    float* __restrict__ sqp,          // [64] partial slot for (side,b,nblk)
    _Float16* lA, _Float16* lB, int nblk)
{
    const int tid = threadIdx.x;      // 256
    const int lane = tid & 63;
    const int wv = tid >> 6;          // 0..3
    const int n0 = nblk * 64;
    const int fr = lane & 15;         // fragment row/col index
    const int kg = lane >> 4;         // 0..3 -> k0 = kg*8

    f32x4 acc[4];
#pragma unroll
    for (int n = 0; n < 4; n++) acc[n] = (f32x4){0.f, 0.f, 0.f, 0.f};

    for (int c0 = 0; c0 < C; c0 += 32) {
        __syncthreads();   // protect LDS reuse from previous step's reads
#pragma unroll
        for (int q = 0; q < 8; q++) {
            int idx = tid + q * 256;          // 0..2047
            int t = idx & 63, c = idx >> 6;   // 64 t x 32 c
            lA[t * APITCH + c] = (_Float16)feat[(size_t)(c0 + c) * NTOK + n0 + t];
        }
#pragma unroll
        for (int q = 0; q < 8; q++) {
            int idx = tid + q * 256;
            int c = idx & 31, h = idx >> 5;   // 64 h x 32 c
            lB[h * APITCH + c] = (_Float16)W[(size_t)h * C + c0 + c];
        }
        __syncthreads();
        half8 a = *(const half8*)&lA[(wv * 16 + fr) * APITCH + kg * 8];
#pragma unroll
        for (int n = 0; n < 4; n++) {
            half8 b = *(const half8*)&lB[(n * 16 + fr) * APITCH + kg * 8];
            acc[n] = __builtin_amdgcn_mfma_f32_16x16x32_f16(a, b, acc[n], 0, 0, 0);
        }
    }

    // Epilogue: D: col=lane&15 -> h, row=(lane>>4)*4+reg -> tok offset.
    __syncthreads();                 // all waves done reading lA/lB this step
    float* sred = (float*)lA;        // reuse staging LDS: [4][64] f32
#pragma unroll
    for (int n = 0; n < 4; n++) {
        const int h = n * 16 + fr;
        const float bv = bias[h];
        float s = 0.f;
#pragma unroll
        for (int reg = 0; reg < 4; reg++) {
            const int tok = wv * 16 + kg * 4 + reg;
            float val = acc[n][reg] + bv;
            out[(size_t)(n0 + tok) * HID + h] = __float2half(val);
            s = fmaf(val, val, s);
        }
        s += __shfl_xor(s, 16, 64);  // sum over kg -> wave's 16-token partial
        s += __shfl_xor(s, 32, 64);
        if (lane < 16) sred[wv * 64 + h] = s;
    }
    __syncthreads();
    if (tid < 64)
        sqp[tid] = sred[tid] + sred[64 + tid] + sred[128 + tid] + sred[192 + tid];
}

__global__ __launch_bounds__(256, 4) void k1_proj(
    const float* __restrict__ feat_s, const float* __restrict__ feat_t,
    const float* __restrict__ Ws, const float* __restrict__ bs,
    const float* __restrict__ Wt, const float* __restrict__ bt,
    __half* __restrict__ xs, __half* __restrict__ xt,
    float* __restrict__ sqpart, float* __restrict__ Pacc,
    int* __restrict__ counters, int* __restrict__ done, float* __restrict__ gsum)
{
    __shared__ __align__(16) _Float16 lA[64 * APITCH];
    __shared__ __align__(16) _Float16 lB[64 * APITCH];
    const int nblk = blockIdx.x, b = blockIdx.y, st = blockIdx.z;
    const int tid = threadIdx.x;

    // ---- workspace init (replaces memset; k1 completes before k4 launches)
    if (st == 0 && nblk < 8) {
        float* pz = Pacc + (size_t)b * NTOK + nblk * 72;
        if (tid < 72) { pz[tid] = 0.f; pz[(size_t)BSZ * NTOK + tid] = 0.f; }
    }
    if (st == 1 && nblk == 0) {
        if (tid < 16) counters[b * 16 + tid] = 0;
        if (b == 0) {
            if (tid == 16) done[0] = 0;
            if (tid == 17) done[1] = 0;
            if (tid == 18) gsum[0] = 0.f;
        }
    }

    if (st == 0) {
        proj_mfma<CS_>(feat_s + (size_t)b * CS_ * NTOK, Ws, bs,
                       xs + (size_t)b * NTOK * HID,
                       sqpart + ((size_t)b * 9 + nblk) * 64, lA, lB, nblk);
    } else {
        proj_mfma<CT_>(feat_t + (size_t)b * CT_ * NTOK, Wt, bt,
                       xt + (size_t)b * NTOK * HID,
                       sqpart + ((size_t)(BSZ + b) * 9 + nblk) * 64, lA, lB, nblk);
    }
}

// ---------------------------------------------------------------------------
// K4: persistent Sinkhorn — R11 protocol (WGB=8, flags, no-return atomics)
// with a FUSED row+col sweep (R3's idea done right): one E pass per iter.
// After the row butterfly every lane holds the full rowsum -> eu locally;
// each wave accumulates its rows' col-partials in 10 REGISTERS (float2[5]),
// writes its private padded vtmp[16][644] slice (plain ds_write, no atomics),
// publisher sums 16 slices. One barrier fewer, E read once not twice, the
// 864-worker perm/fdot2 col pass deleted. launch_bounds(1024,4): 1 WG/CU
// anyway (135KB LDS) -> VGPR cap 128, no spill (R3's failure mode).
// ---------------------------------------------------------------------------
__global__ __launch_bounds__(1024, 4) void k4_sinkhorn(
    const __half* __restrict__ xsh, const __half* __restrict__ xth,
    const float* __restrict__ sqpart, float* __restrict__ Pacc,
    int* __restrict__ counters, int* __restrict__ done,
    float* __restrict__ gsum, float* __restrict__ dummyout,
    float* __restrict__ out)
{
    extern __shared__ char smem[];
    __half* Ms  = (__half*)(smem + L_MS);          // Ms during build, E during iters
    _Float16* MsH = (_Float16*)(smem + L_MS);
    float* u_l  = (float*)(smem + L_U);
    float* vlg  = (float*)(smem + L_V);            // final-only v_log buffer
    float* red  = (float*)(smem + L_RED);
    float* mrow = (float*)(smem + L_MROW);
    _Float16* ewh = (_Float16*)(smem + L_EWH);     // ew_v = 2^v as fp16 per col
    float* vtmp = (float*)(smem + L_VT);           // [16][644] per-wave col partials
    float* ssc  = (float*)(smem + L_UNION);
    float* stc  = (float*)(smem + L_UNION + 256);
    float* sqs  = (float*)(smem + L_UNION + 512);  // 72 f32
    float* sqt  = (float*)(smem + L_UNION + 800);  // 576 f32
    __half* xs_l = (__half*)(smem + L_UNION + 3104);   // 72*68*2 = 9792
    __half* xt_l = (__half*)(smem + L_UNION + 12896);  // 32*68*2 = 4352

    const int tid = threadIdx.x;
    const int b = blockIdx.x & 31, part = blockIdx.x >> 5;   // part 0..7
    const int r0 = part * ROWS;
    const int lane = tid & 63, wv = tid >> 6;
    float s_kept = 0.f;

    if (tid < 64) {
        const float* sp = sqpart + (size_t)b * 9 * 64 + tid;
        float s = 0.f;
#pragma unroll
        for (int k = 0; k < 9; k++) s += sp[k * 64];
        ssc[tid] = 1.0f / fmaxf(sqrtf(s), 1e-12f);
    } else if (tid < 128) {
        const float* sp = sqpart + (size_t)(BSZ + b) * 9 * 64 + (tid - 64);
        float s = 0.f;
#pragma unroll
        for (int k = 0; k < 9; k++) s += sp[k * 64];
        stc[tid - 64] = 1.0f / fmaxf(sqrtf(s), 1e-12f);
    }
    // ewh = 2^v; v starts at 0 -> 1.0 (pad columns: 0 so they contribute nothing)
    for (int m = tid; m < MPITCH; m += 1024) ewh[m] = (m < NTOK) ? (_Float16)1.0f : (_Float16)0.0f;
    __syncthreads();

    for (int idx = tid; idx < ROWS * 64; idx += 1024) {
        int r = idx >> 6, h = idx & 63;
        xs_l[r * XPITCH + h] =
            __float2half(__half2float(xsh[((size_t)b * NTOK + r0 + r) * 64 + h]) * ssc[h]);
    }
    if (tid < NTOK) {
        const __half* tp = xth + ((size_t)b * NTOK + tid) * 64;
        float s = 0.f;
#pragma unroll
        for (int h = 0; h < 64; h++) { float v = __half2float(tp[h]) * stc[h]; s = fmaf(v, v, s); }
        sqt[tid] = s;
    }
    __syncthreads();
    if (tid < ROWS) {
        float s = 0.f;
#pragma unroll
        for (int h = 0; h < 64; h++) { float v = __half2float(xs_l[tid * XPITCH + h]); s = fmaf(v, v, s); }
        sqs[tid] = s;
    }

    for (int c0 = 0; c0 < NTOK; c0 += 32) {
        __syncthreads();
        for (int idx = tid; idx < 32 * 64; idx += 1024) {
            int m = idx >> 6, h = idx & 63;
            xt_l[m * XPITCH + h] =
                __float2half(__half2float(xth[((size_t)b * NTOK + c0 + m) * 64 + h]) * stc[h]);
        }
        __syncthreads();
        for (int idx = tid; idx < ROWS * 32; idx += 1024) {
            int r = idx >> 5, c = idx & 31;
            const __half2* xr = (const __half2*)(xs_l + r * XPITCH);
            const __half2* tr = (const __half2*)(xt_l + c * XPITCH);
            float d = 0.f;
#pragma unroll
            for (int h2 = 0; h2 < 32; h2++) {
                float2 av = __half22float2(xr[h2]);
                float2 tv = __half22float2(tr[h2]);
                d = fmaf(av.x, tv.x, d);
                d = fmaf(av.y, tv.y, d);
            }
            float M = fmaxf(sqs[r] + sqt[c] - 2.f * d, 0.f);
            Ms[r * MPITCH + c0 + c] = __float2half(M * MS_SCALE);
        }
    }
    __syncthreads();
    for (int idx = tid; idx < ROWS * (MPITCH - NTOK); idx += 1024) {
        int r = idx >> 6, k = idx & 63;
        Ms[r * MPITCH + NTOK + k] = __float2half(-1000.f);
    }
    __syncthreads();

    // ---- One-time transform: Ms -> E = 2^(Ms - rowmax), record rowmax.
    for (int r = wv; r < ROWS; r += 16) {
        __half* row = Ms + r * MPITCH;
        float2 f[5];
        float mx = 0.f;   // real Ms >= 0, pad = -1000 never wins
#pragma unroll
        for (int j = 0; j < 5; j++) {
            f[j] = __half22float2(*(const __half2*)&row[128 * j + 2 * lane]);
            mx = fmaxf(mx, fmaxf(f[j].x, f[j].y));
        }
#pragma unroll
        for (int off = 32; off > 0; off >>= 1) mx = fmaxf(mx, __shfl_xor(mx, off, 64));
        if (lane == 0) mrow[r] = mx;
#pragma unroll
        for (int j = 0; j < 5; j++) {
            *(__half2*)&row[128 * j + 2 * lane] = __floats2half2_rn(
                __builtin_amdgcn_exp2f(f[j].x - mx), __builtin_amdgcn_exp2f(f[j].y - mx));
        }
    }
    __syncthreads();

    int* flags = counters + b * 16;   // 8 write-once flags, one 64B line per batch

    for (int it = 1; it <= ITERS; ++it) {
        if (it > 1) {
            if (tid < NTOK) {
                const int qr = (it - 1) & 1, qw = it & 1;
                float s = __hip_atomic_load(&Pacc[(size_t)(qr * BSZ + b) * NTOK + tid],
                                            __ATOMIC_RELAXED, __HIP_MEMORY_SCOPE_AGENT);
                ewh[tid] = (_Float16)(INV_N * __builtin_amdgcn_rcpf(s));   // 2^v
                if (tid >= r0 && tid < r0 + ROWS) {
                    if (s_kept != 0.f)
                        (void)__hip_atomic_fetch_add(
                            &Pacc[(size_t)(qw * BSZ + b) * NTOK + tid], -s_kept,
                            __ATOMIC_RELAXED, __HIP_MEMORY_SCOPE_AGENT);
                    s_kept = s;
                }
            }
            __syncthreads();
        }
        // ---- Fused row+col sweep: ONE pass over E.
        h2f vrh[5];
#pragma unroll
        for (int j = 0; j < 5; j++) vrh[j] = *(const h2f*)&ewh[128 * j + 2 * lane];
        float2 colacc[5];
#pragma unroll
        for (int j = 0; j < 5; j++) colacc[j] = make_float2(0.f, 0.f);

        for (int r = wv; r < ROWS; r += 16) {
            const _Float16* row = MsH + r * MPITCH;
            uint e[5];
            float a = 0.f;
#pragma unroll
            for (int j = 0; j < 5; j++) {
                e[j] = *(const uint*)&row[128 * j + 2 * lane];
                a = fdot2f(__builtin_bit_cast(h2f, e[j]), vrh[j], a);
            }
#pragma unroll
            for (int off = 32; off > 0; off >>= 1) a += __shfl_xor(a, off, 64);
            // every lane holds the full rowsum -> eu locally
            float eu = INV_N * __builtin_amdgcn_rcpf(a);
            if (lane == 0) u_l[r] = -LOG2_N - __builtin_amdgcn_logf(a);
#pragma unroll
            for (int j = 0; j < 5; j++) {
                float2 f = __half22float2(__builtin_bit_cast(__half2, e[j]));
                colacc[j].x = fmaf(f.x, eu, colacc[j].x);
                colacc[j].y = fmaf(f.y, eu, colacc[j].y);
            }
        }
        // write wave-private padded slice (no atomics, overwrite -> no zeroing)
        {
            float* vt = vtmp + wv * VTP;
#pragma unroll
            for (int j = 0; j < 5; j++)
                *(float2*)&vt[128 * j + 2 * lane] = colacc[j];
        }
        __syncthreads();
        // ---- Publish: sum 16 wave slices, one no-return atomic per column
        if (tid < NTOK) {
            float s = 0.f;
#pragma unroll
            for (int w = 0; w < 16; w++) s += vtmp[w * VTP + tid];
            (void)__hip_atomic_fetch_add(&Pacc[(size_t)((it & 1) * BSZ + b) * NTOK + tid], s,
                                         __ATOMIC_RELAXED, __HIP_MEMORY_SCOPE_AGENT);
        }
        __syncthreads();   // drains publishes (vmcnt(0) before s_barrier)
        if (tid < WGB) {
            if (tid == part)
                __hip_atomic_store(&flags[tid], it, __ATOMIC_RELAXED, __HIP_MEMORY_SCOPE_AGENT);
            while (__hip_atomic_load(&flags[tid], __ATOMIC_RELAXED, __HIP_MEMORY_SCOPE_AGENT) < it)
                __builtin_amdgcn_s_sleep(1);
        }
        __syncthreads();
    }

    // ---- Final: v (log2 domain) from Pacc (q=0 holds it=50's sums);
    // T*M with M = (log2(E) + rowmax) * ln2/10
    if (tid < NTOK) {
        float s = __hip_atomic_load(&Pacc[(size_t)b * NTOK + tid],
                                    __ATOMIC_RELAXED, __HIP_MEMORY_SCOPE_AGENT);
        vlg[tid] = -LOG2_N - __builtin_amdgcn_logf(s);
    }
    __syncthreads();
    float acc = 0.f;
    for (int idx = tid; idx < ROWS * NTOK; idx += 1024) {
        int r = idx / NTOK, m = idx - r * NTOK;
        float e = __half2float(Ms[r * MPITCH + m]);
        if (e > 0.f) {
            float msp = __builtin_amdgcn_logf(e) + mrow[r];
            acc = fmaf(__builtin_amdgcn_exp2f(u_l[r] + vlg[m]) * e, msp, acc);
        }
    }
#pragma unroll
    for (int off = 32; off > 0; off >>= 1) acc += __shfl_xor(acc, off, 64);
    if (lane == 0) red[wv] = acc;
    __syncthreads();
    if (tid == 0) {
        float s = 0.f;
#pragma unroll
        for (int w2 = 0; w2 < 16; w2++) s += red[w2];
        float old = __hip_atomic_fetch_add(gsum, s * M_FROM_MSP,
                                           __ATOMIC_RELAXED, __HIP_MEMORY_SCOPE_AGENT);
        int* dptr = done + ((old == -1.2345678e33f) ? 1 : 0);
        int prev = __hip_atomic_fetch_add(dptr, 1, __ATOMIC_RELAXED, __HIP_MEMORY_SCOPE_AGENT);
        if (prev == NWG - 1) {
            float tot = __hip_atomic_load(gsum, __ATOMIC_RELAXED, __HIP_MEMORY_SCOPE_AGENT);
            out[0] = tot * (1.0f / BSZ);
        }
        if (old == -1.2345678e33f) dummyout[blockIdx.x] = 1.f;  // keep param live
    }
}

extern "C" void kernel_launch(void* const* d_in, const int* in_sizes, int n_in,
                              void* d_out, int out_size, void* d_ws, size_t ws_size,
                              hipStream_t stream) {
    const float* feat_s = (const float*)d_in[0];
    const float* feat_t = (const float*)d_in[1];
    const float* Ws = (const float*)d_in[2];
    const float* bs = (const float*)d_in[3];
    const float* Wt = (const float*)d_in[4];
    const float* bt = (const float*)d_in[5];

    char* ws = (char*)d_ws;
    int* counters  = (int*)(ws + OFF_CNT);
    int* done      = (int*)(ws + OFF_DONE);
    float* gsum    = (float*)(ws + OFF_GSUM);
    float* dummyo  = (float*)(ws + OFF_DUMMY);
    float* sqpart  = (float*)(ws + OFF_SQP);
    float* Pacc    = (float*)(ws + OFF_PACC);
    __half* xs     = (__half*)(ws + OFF_XS);
    __half* xt     = (__half*)(ws + OFF_XT);
    float* out = (float*)d_out;

    // no memset dispatch: k1 zeroes flags/done/gsum/Pacc (stream-ordered before k4)

    hipLaunchKernelGGL(k1_proj, dim3(9, 32, 2), dim3(256), 0, stream,
                       feat_s, feat_t, Ws, bs, Wt, bt, xs, xt,
                       sqpart, Pacc, counters, done, gsum);

    (void)hipFuncSetAttribute((const void*)k4_sinkhorn,
                              hipFuncAttributeMaxDynamicSharedMemorySize, SMEM_BYTES);
    hipLaunchKernelGGL(k4_sinkhorn, dim3(NWG), dim3(1024), SMEM_BYTES, stream,
                       xs, xt, sqpart, Pacc, counters, done, gsum, dummyo, out);
}